// Round 3
// baseline (401.971 us; speedup 1.0000x reference)
//
#include <hip/hip_runtime.h>

#define IMG    224
#define NPIX   (IMG * IMG)       // 50176
#define NELEM  (NPIX * 3)        // 150528
#define KSEL   12544             // 0.25 * IMG * IMG
#define NBINS  4096
#define NVEC4  (NELEM / 4)       // 37632 float4 per sample

// ---- K1: histogram ----
#define K1_CHUNKS 4
#define K1_BLOCK  256
#define K1_V4     (NVEC4 / K1_CHUNKS)   // 9408 float4 per block

// ---- K3: classify + apply ----
#define CH        8                     // chunks per sample
#define PIX_PER   (NPIX / CH)           // 6272 pixels per chunk
#define QUADS_PER (PIX_PER / 4)         // 1568 pixel-quads per chunk
#define MWORDS    (PIX_PER / 32)        // 196 mask words

#define CAP 512                          // candidate capacity per sample (mean ~37)

// ============================================================ K1: histogram
// Private per-(sample,chunk) histogram in LDS, flushed with plain uint4
// stores (no global atomics, no global memset needed).
__global__ __launch_bounds__(K1_BLOCK) void k1_hist(
    const float* __restrict__ grad, unsigned int* __restrict__ subhist)
{
    const int s     = blockIdx.x >> 2;
    const int chunk = blockIdx.x & 3;
    const float4* g4 = (const float4*)(grad + (size_t)s * NELEM);

    __shared__ unsigned int h[NBINS];
    for (int i = threadIdx.x; i < NBINS; i += K1_BLOCK) h[i] = 0u;
    __syncthreads();

    const int beg = chunk * K1_V4, end = beg + K1_V4;
    for (int i = beg + threadIdx.x; i < end; i += K1_BLOCK) {
        float4 v = g4[i];
        atomicAdd(&h[min((int)(v.x * 4096.0f), NBINS - 1)], 1u);
        atomicAdd(&h[min((int)(v.y * 4096.0f), NBINS - 1)], 1u);
        atomicAdd(&h[min((int)(v.z * 4096.0f), NBINS - 1)], 1u);
        atomicAdd(&h[min((int)(v.w * 4096.0f), NBINS - 1)], 1u);
    }
    __syncthreads();

    uint4* dst = (uint4*)(subhist + ((size_t)s * K1_CHUNKS + chunk) * NBINS);
    const uint4* hv = (const uint4*)h;
    for (int i = threadIdx.x; i < NBINS / 4; i += K1_BLOCK) dst[i] = hv[i];
}

// ============================================================ K2: sum + suffix scan
__global__ __launch_bounds__(1024) void k2_scan(
    const unsigned int* __restrict__ subhist,
    uint2* __restrict__ thr, unsigned int* __restrict__ candcnt)
{
    const int s   = blockIdx.x;
    const int tid = threadIdx.x;
    const uint4* sh = (const uint4*)(subhist + (size_t)s * K1_CHUNKS * NBINS);

    uint4 a0 = sh[tid];
    uint4 a1 = sh[1024 + tid];
    uint4 a2 = sh[2048 + tid];
    uint4 a3 = sh[3072 + tid];
    const unsigned int h0 = a0.x + a1.x + a2.x + a3.x;
    const unsigned int h1 = a0.y + a1.y + a2.y + a3.y;
    const unsigned int h2 = a0.z + a1.z + a2.z + a3.z;
    const unsigned int h3 = a0.w + a1.w + a2.w + a3.w;
    const unsigned int gsum = h0 + h1 + h2 + h3;

    const int lane = tid & 63, w = tid >> 6;
    unsigned int v = gsum;
    #pragma unroll
    for (int off = 1; off < 64; off <<= 1) {
        unsigned int u = __shfl_down(v, off, 64);
        if (lane + off < 64) v += u;          // wave-local suffix sum
    }
    __shared__ unsigned int wtot[16];
    if (lane == 0) wtot[w] = v;               // wave total
    __syncthreads();
    unsigned int tail = 0;
    for (int i = w + 1; i < 16; ++i) tail += wtot[i];

    const unsigned int suffix     = v + tail;        // sum of groups [tid..1023]
    const unsigned int suffixNext = suffix - gsum;   // sum of groups [tid+1..1023]

    if (suffix >= KSEL && suffixNext < KSEL) {
        unsigned int cum = suffixNext;
        unsigned int hh[4] = {h0, h1, h2, h3};
        for (int i = 3; i >= 0; --i) {
            cum += hh[i];
            if (cum >= KSEL) {
                thr[s] = make_uint2((unsigned)(4 * tid + i),
                                    (unsigned)(KSEL - (cum - hh[i])));
                break;
            }
        }
    }
    if (tid == 0) candcnt[s] = 0u;
}

// ============================================================ K3: classify + apply
__global__ __launch_bounds__(256) void k3_apply(
    const float* __restrict__ data, const float* __restrict__ grad,
    const uint2* __restrict__ thr,
    unsigned int* __restrict__ candcnt,
    unsigned int* __restrict__ candkey, unsigned int* __restrict__ candidx,
    float* __restrict__ out)
{
    const int s     = blockIdx.x >> 3;      // / CH
    const int chunk = blockIdx.x & 7;
    const int p0    = chunk * PIX_PER;
    const int lane  = threadIdx.x & 63;

    const uint2 t  = thr[s];
    const float t0 = (float)t.x * (1.0f / 4096.0f);        // exact (pow2 denom)
    const float t1 = (float)(t.x + 1) * (1.0f / 4096.0f);  // exact

    __shared__ unsigned int mask[MWORDS];   // fully written in phase A, no init

    const float4* g4 = (const float4*)(grad + (size_t)s * NELEM);
    unsigned int* ck = candkey + (size_t)s * CAP;
    unsigned int* ci = candidx + (size_t)s * CAP;

    // ---- phase A: build pixel mask (branchless), collect rare candidates ----
    for (int q = threadIdx.x; q < QUADS_PER; q += 256) {
        const int p = p0 + 4 * q;                 // sample-global pixel of quad
        float4 a = g4[p >> 2];                    // channel-plane 0
        float4 b = g4[(p + NPIX) >> 2];           // plane 1
        float4 c = g4[(p + 2 * NPIX) >> 2];       // plane 2

        unsigned int s1 = 0, s0 = 0;              // bits: [0:3]=a [4:7]=b [8:11]=c
        s1 |= (a.x >= t1) << 0;  s1 |= (a.y >= t1) << 1;
        s1 |= (a.z >= t1) << 2;  s1 |= (a.w >= t1) << 3;
        s1 |= (b.x >= t1) << 4;  s1 |= (b.y >= t1) << 5;
        s1 |= (b.z >= t1) << 6;  s1 |= (b.w >= t1) << 7;
        s1 |= (c.x >= t1) << 8;  s1 |= (c.y >= t1) << 9;
        s1 |= (c.z >= t1) << 10; s1 |= (c.w >= t1) << 11;
        s0 |= (a.x >= t0) << 0;  s0 |= (a.y >= t0) << 1;
        s0 |= (a.z >= t0) << 2;  s0 |= (a.w >= t0) << 3;
        s0 |= (b.x >= t0) << 4;  s0 |= (b.y >= t0) << 5;
        s0 |= (b.z >= t0) << 6;  s0 |= (b.w >= t0) << 7;
        s0 |= (c.x >= t0) << 8;  s0 |= (c.y >= t0) << 9;
        s0 |= (c.z >= t0) << 10; s0 |= (c.w >= t0) << 11;

        // pixel nibble: any channel selected
        unsigned int m = (s1 | (s1 >> 4) | (s1 >> 8)) & 0xFu;

        // octet shuffle-OR: lanes 8m..8m+7 combine nibbles into one mask word
        unsigned int wword = m << (4 * (lane & 7));
        wword |= __shfl_xor(wword, 1, 64);
        wword |= __shfl_xor(wword, 2, 64);
        wword |= __shfl_xor(wword, 4, 64);
        if ((lane & 7) == 0) mask[q >> 3] = wword;   // sole owner, no atomic

        // bin == B1 candidates (rare: ~37 per 150528 elements)
        unsigned int candm = s0 & ~s1;
        if (candm) {
            do {
                const int j  = __ffs(candm) - 1;
                candm &= candm - 1;
                const int pl = j >> 2, e = j & 3;
                const float4 src = (pl == 0) ? a : (pl == 1) ? b : c;
                const float val = (e == 0) ? src.x : (e == 1) ? src.y
                                : (e == 2) ? src.z : src.w;
                const unsigned int cc = atomicAdd(&candcnt[s], 1u);
                if (cc < CAP) {
                    ck[cc] = __float_as_uint(val);   // nonneg: uint order == float order
                    ci[cc] = (unsigned int)(pl * NPIX + p + e);
                }
            } while (candm);
        }
    }
    __syncthreads();

    // ---- phase B: masked copy, pixel-quad aligned (no divisions) ----
    const float4* d4 = (const float4*)(data + (size_t)s * NELEM + (size_t)3 * p0);
    float4*       o4 = (float4*)(out  + (size_t)s * NELEM + (size_t)3 * p0);
    for (int q = threadIdx.x; q < QUADS_PER; q += 256) {
        const unsigned int bits = (mask[q >> 3] >> (4 * (q & 7))) & 0xFu;
        float4 v0 = d4[3 * q];
        float4 v1 = d4[3 * q + 1];
        float4 v2 = d4[3 * q + 2];
        if (bits & 1u) { v0.x = 0.0f; v0.y = 0.0f; v0.z = 0.0f; }
        if (bits & 2u) { v0.w = 0.0f; v1.x = 0.0f; v1.y = 0.0f; }
        if (bits & 4u) { v1.z = 0.0f; v1.w = 0.0f; v2.x = 0.0f; }
        if (bits & 8u) { v2.y = 0.0f; v2.z = 0.0f; v2.w = 0.0f; }
        o4[3 * q]     = v0;
        o4[3 * q + 1] = v1;
        o4[3 * q + 2] = v2;
    }
}

// ============================================================ K4: exact tie ranking
__global__ __launch_bounds__(64) void k4_ties(
    const uint2* __restrict__ thr, const unsigned int* __restrict__ candcnt,
    const unsigned int* __restrict__ candkey, const unsigned int* __restrict__ candidx,
    float* __restrict__ out)
{
    const int s = blockIdx.x;
    const unsigned int n = min(candcnt[s], (unsigned int)CAP);
    const unsigned int r = thr[s].y;
    const unsigned int* ck = candkey + (size_t)s * CAP;
    const unsigned int* ci = candidx + (size_t)s * CAP;

    __shared__ unsigned int k_[CAP], i_[CAP];
    for (unsigned int i = threadIdx.x; i < n; i += 64) { k_[i] = ck[i]; i_[i] = ci[i]; }
    __syncthreads();

    float* o = out + (size_t)s * NELEM;
    for (unsigned int j = threadIdx.x; j < n; j += 64) {
        const unsigned int kj = k_[j], ij = i_[j];
        unsigned int rank = 0;
        for (unsigned int i = 0; i < n; ++i)
            rank += (k_[i] > kj) || (k_[i] == kj && i_[i] < ij);
        if (rank < r) {   // selected: (value desc, index asc) — jax.lax.top_k order
            const int p = (int)(ij % NPIX);
            o[3 * p] = 0.0f; o[3 * p + 1] = 0.0f; o[3 * p + 2] = 0.0f;
        }
    }
}

// ============================================================ fallback (round-1 monolith)
#define MAXCAND 2048
#define NMASKW (NPIX / 32)
#define BLOCK  1024

__global__ __launch_bounds__(BLOCK) void masked_model_kernel(
    const float* __restrict__ data,
    const float* __restrict__ grad,
    float* __restrict__ out)
{
    const int b   = blockIdx.x;
    const int tid = threadIdx.x;

    const float* g = grad + (size_t)b * NELEM;
    const float* d = data + (size_t)b * NELEM;
    float*       o = out  + (size_t)b * NELEM;

    __shared__ unsigned int hist[NBINS];
    __shared__ unsigned int suffixP[BLOCK + 1];
    __shared__ unsigned int mask[NMASKW];
    __shared__ unsigned int candkey[MAXCAND];
    __shared__ unsigned int candidx[MAXCAND];
    __shared__ unsigned int candcnt;
    __shared__ int sB1;
    __shared__ unsigned int sR;

    for (int i = tid; i < NBINS; i += BLOCK) hist[i] = 0u;
    for (int i = tid; i < NMASKW; i += BLOCK) mask[i] = 0u;
    if (tid == 0) { candcnt = 0u; suffixP[BLOCK] = 0u; }
    __syncthreads();

    const float4* g4 = (const float4*)g;
    for (int i = tid; i < NVEC4; i += BLOCK) {
        float4 v = g4[i];
        atomicAdd(&hist[min((int)(v.x * 4096.0f), NBINS - 1)], 1u);
        atomicAdd(&hist[min((int)(v.y * 4096.0f), NBINS - 1)], 1u);
        atomicAdd(&hist[min((int)(v.z * 4096.0f), NBINS - 1)], 1u);
        atomicAdd(&hist[min((int)(v.w * 4096.0f), NBINS - 1)], 1u);
    }
    __syncthreads();

    {
        unsigned int sv = hist[4 * tid] + hist[4 * tid + 1]
                        + hist[4 * tid + 2] + hist[4 * tid + 3];
        suffixP[tid] = sv;
        __syncthreads();
        for (int off = 1; off < BLOCK; off <<= 1) {
            unsigned int v = suffixP[tid];
            if (tid + off < BLOCK) v += suffixP[tid + off];
            __syncthreads();
            suffixP[tid] = v;
            __syncthreads();
        }
    }
    {
        unsigned int a  = suffixP[tid];
        unsigned int nx = suffixP[tid + 1];
        if (a >= KSEL && nx < KSEL) {
            unsigned int cum = nx;
            for (int i = 3; i >= 0; --i) {
                unsigned int h = hist[4 * tid + i];
                cum += h;
                if (cum >= KSEL) { sB1 = 4 * tid + i; sR = KSEL - (cum - h); break; }
            }
        }
    }
    __syncthreads();

    {
        const int B1 = sB1;
        for (int i = tid; i < NVEC4; i += BLOCK) {
            float4 v = g4[i];
            int base = 4 * i;
            float vv[4] = {v.x, v.y, v.z, v.w};
            #pragma unroll
            for (int c = 0; c < 4; ++c) {
                int bin = min((int)(vv[c] * 4096.0f), NBINS - 1);
                if (bin > B1) {
                    int p = (base + c) % NPIX;
                    atomicOr(&mask[p >> 5], 1u << (p & 31));
                } else if (bin == B1) {
                    unsigned int c2 = atomicAdd(&candcnt, 1u);
                    if (c2 < MAXCAND) {
                        candkey[c2] = __float_as_uint(vv[c]);
                        candidx[c2] = (unsigned int)(base + c);
                    }
                }
            }
        }
    }
    __syncthreads();

    {
        unsigned int n = candcnt < MAXCAND ? candcnt : MAXCAND;
        unsigned int r = sR;
        for (unsigned int j = tid; j < n; j += BLOCK) {
            unsigned int kj = candkey[j];
            unsigned int ij = candidx[j];
            unsigned int rank = 0;
            for (unsigned int i = 0; i < n; ++i) {
                unsigned int ki = candkey[i];
                rank += (ki > kj) || (ki == kj && candidx[i] < ij);
            }
            if (rank < r) {
                int p = (int)(ij % NPIX);
                atomicOr(&mask[p >> 5], 1u << (p & 31));
            }
        }
    }
    __syncthreads();

    {
        const float4* d4 = (const float4*)d;
        float4*       o4 = (float4*)o;
        for (int i = tid; i < NVEC4; i += BLOCK) {
            float4 v = d4[i];
            int e = 4 * i;
            int p0 = e / 3, p1 = (e + 1) / 3, p2 = (e + 2) / 3, p3 = (e + 3) / 3;
            if ((mask[p0 >> 5] >> (p0 & 31)) & 1u) v.x = 0.0f;
            if ((mask[p1 >> 5] >> (p1 & 31)) & 1u) v.y = 0.0f;
            if ((mask[p2 >> 5] >> (p2 & 31)) & 1u) v.z = 0.0f;
            if ((mask[p3 >> 5] >> (p3 & 31)) & 1u) v.w = 0.0f;
            o4[i] = v;
        }
    }
}

// ============================================================ launch
extern "C" void kernel_launch(void* const* d_in, const int* in_sizes, int n_in,
                              void* d_out, int out_size, void* d_ws, size_t ws_size,
                              hipStream_t stream) {
    const float* data = (const float*)d_in[0];   // [B, 224, 224, 3] fp32
    const float* grad = (const float*)d_in[1];   // [B, 150528] fp32
    float* out = (float*)d_out;

    const int B = in_sizes[0] / NELEM;

    const size_t subB = (size_t)B * K1_CHUNKS * NBINS * sizeof(unsigned int); // 16.8 MB @ B=256
    const size_t thrB = (size_t)B * sizeof(uint2);
    const size_t cntB = (size_t)B * sizeof(unsigned int);
    const size_t cntPad = (cntB + 7) & ~(size_t)7;
    const size_t keyB = (size_t)B * CAP * sizeof(unsigned int);

    char* p = (char*)d_ws;
    unsigned int* subhist = (unsigned int*)p;  p += subB;
    uint2*        thr     = (uint2*)p;         p += thrB;
    unsigned int* cnt     = (unsigned int*)p;  p += cntPad;
    unsigned int* ckey    = (unsigned int*)p;  p += keyB;
    unsigned int* cidx    = (unsigned int*)p;  p += keyB;
    const size_t need = (size_t)(p - (char*)d_ws);

    if (ws_size >= need) {
        k1_hist<<<B * K1_CHUNKS, K1_BLOCK, 0, stream>>>(grad, subhist);
        k2_scan<<<B, 1024, 0, stream>>>(subhist, thr, cnt);
        k3_apply<<<B * CH, 256, 0, stream>>>(data, grad, thr, cnt, ckey, cidx, out);
        k4_ties<<<B, 64, 0, stream>>>(thr, cnt, ckey, cidx, out);
    } else {
        // scratch too small: proven single-kernel path
        masked_model_kernel<<<B, BLOCK, 0, stream>>>(data, grad, out);
    }
}